// Round 10
// baseline (531.495 us; speedup 1.0000x reference)
//
#include <hip/hip_runtime.h>
#include <math.h>

#define NE 32
#define NN 8
#define EMB 256
#define TPS 32
#define E_SAME 480
#define E_ANTI 512
#define E_NE 256

// ---- ws layout (shorts) ----
#define AU1_OFF 0
#define AU2_OFF 3072
#define AW1_OFF 6144
#define AW2_OFF 9216
#define H1T_OFF 12288
#define H2T_OFF 36864
#define BIAS_OFF 39936
#define G1_OFF 40512
#define G2_OFF 130624

typedef float f32x4 __attribute__((ext_vector_type(4)));
typedef short s16x4 __attribute__((ext_vector_type(4)));
typedef short s16x8 __attribute__((ext_vector_type(8)));

__device__ __forceinline__ short f2bf(float x) {
    unsigned u = __builtin_bit_cast(unsigned, x);
    u += 0x7fffu + ((u >> 16) & 1u);
    return (short)(u >> 16);
}
__device__ __forceinline__ float bf2f(short h) {
    unsigned u = ((unsigned)(unsigned short)h) << 16;
    return __builtin_bit_cast(float, u);
}
__device__ __forceinline__ float fast_tanh(float x) {
    float e = __builtin_amdgcn_exp2f(x * 2.8853900817779268f);
    return 1.f - 2.f * __builtin_amdgcn_rcpf(e + 1.f);
}
__device__ __forceinline__ s16x8 pack8(f32x4 a, f32x4 b) {
    s16x8 r = { f2bf(a[0]), f2bf(a[1]), f2bf(a[2]), f2bf(a[3]),
                f2bf(b[0]), f2bf(b[1]), f2bf(b[2]), f2bf(b[3]) };
    return r;
}
__device__ __forceinline__ f32x4 mfma32(s16x8 a, s16x8 b, f32x4 c) {
    return __builtin_amdgcn_mfma_f32_16x16x32_bf16(a, b, c, 0, 0, 0);
}
__device__ __forceinline__ f32x4 mfma16(s16x4 a, s16x4 b, f32x4 c) {
#if __has_builtin(__builtin_amdgcn_mfma_f32_16x16x16bf16_1k)
    return __builtin_amdgcn_mfma_f32_16x16x16bf16_1k(a, b, c, 0, 0, 0);
#else
    asm volatile("v_mfma_f32_16x16x16_bf16 %0, %1, %2, %0" : "+v"(c) : "v"(a), "v"(b));
    return c;
#endif
}

// async global->LDS 16B per lane; fallback keeps correctness if builtin absent.
#if __has_builtin(__builtin_amdgcn_global_load_lds)
#define HAVE_GLL 1
__device__ __forceinline__ void stage16(const void* g, void* l) {
    __builtin_amdgcn_global_load_lds((const __attribute__((address_space(1))) void*)g,
                                     (__attribute__((address_space(3))) void*)l, 16, 0, 0);
}
#else
#define HAVE_GLL 0
__device__ __forceinline__ void stage16(const void* g, void* l) {
    *(f32x4*)l = *(const f32x4*)g;
}
#endif

__global__ void prep_weights(const float* __restrict__ u_w1, const float* __restrict__ u_w2,
                             const float* __restrict__ w_w1, const float* __restrict__ w_w2,
                             const float* __restrict__ h_w1, const float* __restrict__ h_w2,
                             const float* __restrict__ u_b1, const float* __restrict__ u_b2,
                             const float* __restrict__ w_b1, const float* __restrict__ w_b2,
                             const float* __restrict__ h_b1, const float* __restrict__ h_b2,
                             const float* __restrict__ g_w1, const float* __restrict__ g_w2,
                             short* __restrict__ wsb)
{
    int tile = blockIdx.x, lane = threadIdx.x;
    int g = lane >> 4, q = lane & 15;
    if (tile < 6) {
        int t = tile >> 1, mt = tile & 1;
        const float* src = u_w1 + t * 1024;
        short* dst = wsb + AU1_OFF + tile * 512 + lane * 8;
        #pragma unroll
        for (int i = 0; i < 8; ++i) dst[i] = f2bf(src[(8 * g + i) * 32 + mt * 16 + q]);
    } else if (tile < 42) {
        int m = (tile - 6) / 12, idx = (tile - 6) % 12;
        int mt = (idx >> 1) & 1, ks = idx & 1, t = idx >> 2;
        const float* mp = (m == 0) ? u_w2 : (m == 1) ? w_w1 : w_w2;
        const float* src = mp + t * 1024;
        short* dst = wsb + AU2_OFF + m * 3072 + idx * 256 + lane * 4;
        #pragma unroll
        for (int i = 0; i < 4; ++i) dst[i] = f2bf(src[(ks * 16 + 4 * g + i) * 32 + mt * 16 + q]);
    } else if (tile < 90) {
        int idx = tile - 42;
        int t = idx >> 4, r = idx & 15, mt = r >> 3, ks = r & 7;
        const float* src = h_w1 + t * 8192;
        short* dst = wsb + H1T_OFF + idx * 512 + lane * 8;
        #pragma unroll
        for (int i = 0; i < 8; ++i) dst[i] = f2bf(src[(ks * 32 + 8 * g + i) * 32 + mt * 16 + q]);
    } else if (tile < 102) {
        int idx = tile - 90;
        int t = idx >> 2, mt = (idx >> 1) & 1, ks = idx & 1;
        const float* src = h_w2 + t * 1024;
        short* dst = wsb + H2T_OFF + idx * 256 + lane * 4;
        #pragma unroll
        for (int i = 0; i < 4; ++i) dst[i] = f2bf(src[(ks * 16 + 4 * g + i) * 32 + mt * 16 + q]);
    } else if (tile == 102) {
        const float* bsrc[6] = {u_b1, u_b2, w_b1, w_b2, h_b1, h_b2};
        for (int j = lane; j < 576; j += 64)
            wsb[BIAS_OFF + j] = f2bf(bsrc[j / 96][j % 96]);
    } else if (tile < 279) {
        int idx = tile - 103, nt = idx / 11, ks = idx % 11;
        short* dst = wsb + G1_OFF + idx * 512 + lane * 8;
        #pragma unroll
        for (int i = 0; i < 8; ++i)
            dst[i] = f2bf(g_w1[(size_t)(ks * 32 + 8 * g + i) * 256 + nt * 16 + q]);
    } else {
        int idx = tile - 279;
        short* dst = wsb + G2_OFF + idx * 512 + lane * 8;
        int nt = idx >> 3, ks = idx & 7;
        #pragma unroll
        for (int i = 0; i < 8; ++i)
            dst[i] = f2bf(g_w2[(size_t)(ks * 32 + 8 * g + i) * 256 + nt * 16 + q]);
    }
}

// One 16-edge tile through u/w MLPs + scatter. [R6-verified sequence]
#define TILE_MLP(V0, V1, RL, RH, SE, RE, LIVE)                                    \
{                                                                                 \
    s16x8 B32 = pack8(V0, V1);                                                    \
    f32x4 c0 = {0.f,0.f,0.f,0.f}, c1 = {0.f,0.f,0.f,0.f};                         \
    c0 = mfma32(Au1_0, B32, c0);                                                  \
    c1 = mfma32(Au1_1, B32, c1);                                                  \
    s16x4 p0, p1;                                                                 \
    _Pragma("unroll")                                                             \
    for (int r = 0; r < 4; ++r) {                                                 \
        p0[r] = f2bf(fast_tanh(c0[r] + bf2f(bb1l[r])));                           \
        p1[r] = f2bf(fast_tanh(c1[r] + bf2f(bb1h[r])));                           \
    }                                                                             \
    f32x4 d0 = {0.f,0.f,0.f,0.f}, d1 = {0.f,0.f,0.f,0.f};                         \
    d0 = mfma16(Au2_[0], p0, d0); d0 = mfma16(Au2_[1], p1, d0);                   \
    d1 = mfma16(Au2_[2], p0, d1); d1 = mfma16(Au2_[3], p1, d1);                   \
    const float* rlp_ = (const float*)&RL; const float* rhp_ = (const float*)&RH; \
    _Pragma("unroll")                                                             \
    for (int r = 0; r < 4; ++r) {                                                 \
        p0[r] = f2bf(rlp_[r] + d0[r] + bf2f(bb2l[r]));                            \
        p1[r] = f2bf(rhp_[r] + d1[r] + bf2f(bb2h[r]));                            \
    }                                                                             \
    d0 = (f32x4){0.f,0.f,0.f,0.f}; d1 = (f32x4){0.f,0.f,0.f,0.f};                 \
    d0 = mfma16(Aw1_[0], p0, d0); d0 = mfma16(Aw1_[1], p1, d0);                   \
    d1 = mfma16(Aw1_[2], p0, d1); d1 = mfma16(Aw1_[3], p1, d1);                   \
    _Pragma("unroll")                                                             \
    for (int r = 0; r < 4; ++r) {                                                 \
        p0[r] = f2bf(fast_tanh(d0[r] + bf2f(bb3l[r])));                           \
        p1[r] = f2bf(fast_tanh(d1[r] + bf2f(bb3h[r])));                           \
    }                                                                             \
    d0 = (f32x4){0.f,0.f,0.f,0.f}; d1 = (f32x4){0.f,0.f,0.f,0.f};                 \
    d0 = mfma16(Aw2_[0], p0, d0); d0 = mfma16(Aw2_[1], p1, d0);                   \
    d1 = mfma16(Aw2_[2], p0, d1); d1 = mfma16(Aw2_[3], p1, d1);                   \
    if (LIVE) {                                                                   \
        s16x4 hlo = *(const s16x4*)(hxt + (SE) * 36 + 4 * g);                     \
        s16x4 hhi = *(const s16x4*)(hxt + (SE) * 36 + 16 + 4 * g);                \
        float* zr = z_s + (RE) * 97 + zc0 + 4 * g;                                \
        _Pragma("unroll")                                                         \
        for (int r = 0; r < 4; ++r) {                                             \
            atomicAdd(zr + r,      (d0[r] + bf2f(bb4l[r])) * bf2f(hlo[r]));       \
            atomicAdd(zr + 16 + r, (d1[r] + bf2f(bb4h[r])) * bf2f(hhi[r]));       \
        }                                                                         \
    }                                                                             \
}

// LDS: f[32][356]=22784 ; z[32][97]=12416 ; hx[72][36]=5184 ; stage ring 4wv*3*2048=24576
// total 64960. Phase E: H[32][260] overlays z+hx.
__launch_bounds__(256, 2)
__global__ void gnn_kernel(
    const float* __restrict__ elec, const float* __restrict__ nuc,
    const float* __restrict__ fs,  const float* __restrict__ fa,  const float* __restrict__ fn,
    const float* __restrict__ g_b1, const float* __restrict__ g_b2,
    const int* __restrict__ ss, const int* __restrict__ rs,
    const int* __restrict__ sa, const int* __restrict__ ra,
    const int* __restrict__ sn, const int* __restrict__ rn,
    const short* __restrict__ wsb,
    float* __restrict__ out)
{
    __shared__ __align__(16) char smem[64960];
    short* f_s  = (short*)smem;                  // [32][356]
    float* z_s  = (float*)(smem + 22784);        // [32][97]
    short* hx_s = (short*)(smem + 35200);        // [72][36]
    short* H_s  = (short*)(smem + 22784);        // [32][260] (phase E overlay)

    const int tid  = threadIdx.x;
    const int b    = blockIdx.x;
    const int lane = tid & 63, wv = tid >> 6;
    const int g    = lane >> 4, q = lane & 15;

    // swizzle constants: LDS[x] = G[swz(x)], swz(x) = x ^ (((x>>7)&7)<<4)
    const int loff1 = (lane * 16) ^ (((lane >> 3) & 7) << 4);   // staging src, slots 0..63
    const int kq    = (q & 7) << 4;
    const int av0 = (q * 128 + g * 32) ^ kq;
    const int av1 = (q * 128 + g * 32 + 16) ^ kq;
    const int arl = (q * 128 + g * 16) ^ kq;
    const int arh = (q * 128 + 64 + g * 16) ^ kq;
    char* ringBase = smem + 40384 + wv * 6144;   // 3 slots x 2048B per wave

    // ---------- Phase A ----------
    if (wv > 0)
        for (int i = tid - 64; i < 32 * 97; i += 192) z_s[i] = 0.f;

    #pragma unroll 1
    for (int task = wv; task < 5; task += 4) {
        int t, nt;
        if (task < 4) { t = task >> 1; nt = task & 1; }
        else          { t = 2; nt = 0; }
        const float* rowp = (t < 2) ? elec + ((size_t)b * NE + nt * 16 + q) * EMB
                                    : nuc  + ((size_t)b * NN + (q < 8 ? q : 7)) * EMB;
        f32x4 c0 = {0.f, 0.f, 0.f, 0.f}, c1 = {0.f, 0.f, 0.f, 0.f};
        const short* wA = wsb + H1T_OFF + t * 16 * 512;
        #pragma unroll
        for (int ks = 0; ks < 8; ++ks) {
            f32x4 v0 = *(const f32x4*)(rowp + 32 * ks + 8 * g);
            f32x4 v1 = *(const f32x4*)(rowp + 32 * ks + 8 * g + 4);
            s16x8 Bf = pack8(v0, v1);
            if (t == 0) {
                int off = (nt * 16 + q) * 356 + 32 * ks + 8 * g;
                *(s16x4*)(f_s + off)     = __builtin_shufflevector(Bf, Bf, 0, 1, 2, 3);
                *(s16x4*)(f_s + off + 4) = __builtin_shufflevector(Bf, Bf, 4, 5, 6, 7);
            }
            s16x8 a0 = *(const s16x8*)(wA + ks * 512 + lane * 8);
            s16x8 a1 = *(const s16x8*)(wA + (8 + ks) * 512 + lane * 8);
            c0 = mfma32(a0, Bf, c0);
            c1 = mfma32(a1, Bf, c1);
        }
        s16x4 b1l = *(const s16x4*)(wsb + BIAS_OFF + (12 + t) * 32 + 4 * g);
        s16x4 b1h = *(const s16x4*)(wsb + BIAS_OFF + (12 + t) * 32 + 16 + 4 * g);
        s16x4 p0, p1;
        #pragma unroll
        for (int r = 0; r < 4; ++r) {
            p0[r] = f2bf(fast_tanh(c0[r] + bf2f(b1l[r])));
            p1[r] = f2bf(fast_tanh(c1[r] + bf2f(b1h[r])));
        }
        const short* wA2 = wsb + H2T_OFF + t * 4 * 256;
        f32x4 d0 = {0.f, 0.f, 0.f, 0.f}, d1 = {0.f, 0.f, 0.f, 0.f};
        d0 = mfma16(*(const s16x4*)(wA2 + 0 * 256 + lane * 4), p0, d0);
        d0 = mfma16(*(const s16x4*)(wA2 + 1 * 256 + lane * 4), p1, d0);
        d1 = mfma16(*(const s16x4*)(wA2 + 2 * 256 + lane * 4), p0, d1);
        d1 = mfma16(*(const s16x4*)(wA2 + 3 * 256 + lane * 4), p1, d1);
        if (t < 2 || q < 8) {
            s16x4 b2l = *(const s16x4*)(wsb + BIAS_OFF + (15 + t) * 32 + 4 * g);
            s16x4 b2h = *(const s16x4*)(wsb + BIAS_OFF + (15 + t) * 32 + 16 + 4 * g);
            s16x4 w0, w1;
            #pragma unroll
            for (int r = 0; r < 4; ++r) {
                w0[r] = f2bf(d0[r] + bf2f(b2l[r]));
                w1[r] = f2bf(d1[r] + bf2f(b2h[r]));
            }
            int row = t * 32 + nt * 16 + q;
            *(s16x4*)(hx_s + row * 36 + 4 * g)      = w0;
            *(s16x4*)(hx_s + row * 36 + 16 + 4 * g) = w1;
        }
    }
    __syncthreads();

    // ---------- Phase C: edge MLPs from LDS-staged feats (counted-vmcnt ring) ----------
    #pragma unroll 1
    for (int t = 0; t < 3; ++t) {
        const float* ft; const int* snd; const int* rcv; int cnt, zc0;
        if (t == 0)      { ft = fs; snd = ss; rcv = rs; cnt = E_SAME; zc0 = 32; }
        else if (t == 1) { ft = fa; snd = sa; rcv = ra; cnt = E_ANTI; zc0 = 64; }
        else             { ft = fn; snd = sn; rcv = rn; cnt = E_NE;   zc0 = 0;  }
        s16x8 Au1_0 = *(const s16x8*)(wsb + AU1_OFF + (t * 2 + 0) * 512 + lane * 8);
        s16x8 Au1_1 = *(const s16x8*)(wsb + AU1_OFF + (t * 2 + 1) * 512 + lane * 8);
        s16x4 Au2_[4], Aw1_[4], Aw2_[4];
        #pragma unroll
        for (int i = 0; i < 4; ++i) {
            Au2_[i] = *(const s16x4*)(wsb + AU2_OFF + (t * 4 + i) * 256 + lane * 4);
            Aw1_[i] = *(const s16x4*)(wsb + AW1_OFF + (t * 4 + i) * 256 + lane * 4);
            Aw2_[i] = *(const s16x4*)(wsb + AW2_OFF + (t * 4 + i) * 256 + lane * 4);
        }
        s16x4 bb1l = *(const s16x4*)(wsb + BIAS_OFF + (0 + t) * 32 + 4 * g);
        s16x4 bb1h = *(const s16x4*)(wsb + BIAS_OFF + (0 + t) * 32 + 16 + 4 * g);
        s16x4 bb2l = *(const s16x4*)(wsb + BIAS_OFF + (3 + t) * 32 + 4 * g);
        s16x4 bb2h = *(const s16x4*)(wsb + BIAS_OFF + (3 + t) * 32 + 16 + 4 * g);
        s16x4 bb3l = *(const s16x4*)(wsb + BIAS_OFF + (6 + t) * 32 + 4 * g);
        s16x4 bb3h = *(const s16x4*)(wsb + BIAS_OFF + (6 + t) * 32 + 16 + 4 * g);
        s16x4 bb4l = *(const s16x4*)(wsb + BIAS_OFF + (9 + t) * 32 + 4 * g);
        s16x4 bb4h = *(const s16x4*)(wsb + BIAS_OFF + (9 + t) * 32 + 16 + 4 * g);
        const short* hxt = hx_s + t * 32 * 36;

        const int real = cnt >> 4;               // 30, 32, 16
        const int NT   = (real + 3) >> 2;        // 8, 8, 4 (uniform across waves)
        const char* ftb = (const char*)(ft + (size_t)b * cnt * TPS);

        // stage level L into slot L%3 (tile index clamped; dead tiles LIVE-guarded)
        #define STAGE_LVL(L)                                                      \
        {                                                                         \
            int tl_ = wv + 4 * (L); if (tl_ >= real) tl_ = real - 1;              \
            const char* s_ = ftb + (size_t)tl_ * 2048;                            \
            char* d_ = ringBase + ((L) % 3) * 2048;                               \
            stage16(s_ + loff1, d_ + lane * 16);                                  \
            stage16(s_ + 1024 + loff1, d_ + 1024 + lane * 16);                    \
        }

        STAGE_LVL(0);
        STAGE_LVL(1);

        #pragma unroll 1
        for (int jj = 0; jj < NT; ++jj) {
            int tile = wv + 4 * jj;
            int live = (tile < real);
            int ct   = live ? tile : real - 1;
            int se = snd[ct * 16 + q], re = rcv[ct * 16 + q];
            if (jj + 2 < NT) STAGE_LVL(jj + 2);
#if HAVE_GLL
            // drain buf jj's stage; keep levels jj+1, jj+2 (+ this iter's idx) in flight
            if (jj + 2 < NT)      asm volatile("s_waitcnt vmcnt(6)" ::: "memory");
            else if (jj + 1 < NT) asm volatile("s_waitcnt vmcnt(4)" ::: "memory");
            else                  asm volatile("s_waitcnt vmcnt(2)" ::: "memory");
            __builtin_amdgcn_sched_barrier(0);
#endif
            const char* sb = ringBase + (jj % 3) * 2048;
            f32x4 v0 = *(const f32x4*)(sb + av0);
            f32x4 v1 = *(const f32x4*)(sb + av1);
            f32x4 rl = *(const f32x4*)(sb + arl);
            f32x4 rh = *(const f32x4*)(sb + arh);
            TILE_MLP(v0, v1, rl, rh, se, re, live);
        }
        #undef STAGE_LVL
    }
    __syncthreads();

    // ---------- Phase D ----------
    for (int i = tid; i < 32 * 96; i += 256) {
        int r = i / 96, c = i - r * 96;
        float sc = (c < 32) ? 0.125f : ((c < 64) ? (1.f / 15.f) : (1.f / 16.f));
        f_s[r * 356 + 256 + c] = f2bf(z_s[r * 97 + c] * sc);
    }
    __syncthreads();

    // ---------- Phase E layer1 ----------
    #pragma unroll 1
    for (int task = wv; task < 32; task += 4) {
        int mt = task >> 4, nt = task & 15;
        f32x4 acc = {0.f, 0.f, 0.f, 0.f};
        const short* ar = f_s + (mt * 16 + q) * 356 + 8 * g;
        const short* wp = wsb + G1_OFF + nt * 11 * 512 + lane * 8;
        #pragma unroll
        for (int ks = 0; ks < 11; ++ks) {
            s16x4 alo = *(const s16x4*)(ar + 32 * ks);
            s16x4 ahi = *(const s16x4*)(ar + 32 * ks + 4);
            s16x8 a = __builtin_shufflevector(alo, ahi, 0, 1, 2, 3, 4, 5, 6, 7);
            s16x8 bw = *(const s16x8*)(wp + ks * 512);
            acc = mfma32(a, bw, acc);
        }
        float bias = g_b1[nt * 16 + q];
        #pragma unroll
        for (int r = 0; r < 4; ++r)
            H_s[(mt * 16 + 4 * g + r) * 260 + nt * 16 + q] = f2bf(fast_tanh(acc[r] + bias));
    }
    __syncthreads();

    // ---------- Phase E layer2 ----------
    #pragma unroll 1
    for (int task = wv; task < 32; task += 4) {
        int mt = task >> 4, nt = task & 15;
        f32x4 acc = {0.f, 0.f, 0.f, 0.f};
        const short* ar = H_s + (mt * 16 + q) * 260 + 8 * g;
        const short* wp = wsb + G2_OFF + nt * 8 * 512 + lane * 8;
        #pragma unroll
        for (int ks = 0; ks < 8; ++ks) {
            s16x4 alo = *(const s16x4*)(ar + 32 * ks);
            s16x4 ahi = *(const s16x4*)(ar + 32 * ks + 4);
            s16x8 a = __builtin_shufflevector(alo, ahi, 0, 1, 2, 3, 4, 5, 6, 7);
            s16x8 bw = *(const s16x8*)(wp + ks * 512);
            acc = mfma32(a, bw, acc);
        }
        float bias = g_b2[nt * 16 + q];
        #pragma unroll
        for (int r = 0; r < 4; ++r) {
            int row = mt * 16 + 4 * g + r, col = nt * 16 + q;
            size_t o = ((size_t)b * NE + row) * EMB + col;
            out[o] = bf2f(f_s[row * 356 + col]) + acc[r] + bias;
        }
    }
}

extern "C" void kernel_launch(void* const* d_in, const int* in_sizes, int n_in,
                              void* d_out, int out_size, void* d_ws, size_t ws_size,
                              hipStream_t stream) {
    const float* elec = (const float*)d_in[0];
    const float* nuc  = (const float*)d_in[1];
    const float* fs   = (const float*)d_in[2];
    const float* fa   = (const float*)d_in[3];
    const float* fn   = (const float*)d_in[4];
    const float* u_w1 = (const float*)d_in[5];
    const float* u_b1 = (const float*)d_in[6];
    const float* u_w2 = (const float*)d_in[7];
    const float* u_b2 = (const float*)d_in[8];
    const float* w_w1 = (const float*)d_in[9];
    const float* w_b1 = (const float*)d_in[10];
    const float* w_w2 = (const float*)d_in[11];
    const float* w_b2 = (const float*)d_in[12];
    const float* h_w1 = (const float*)d_in[13];
    const float* h_b1 = (const float*)d_in[14];
    const float* h_w2 = (const float*)d_in[15];
    const float* h_b2 = (const float*)d_in[16];
    const float* g_w1 = (const float*)d_in[17];
    const float* g_b1 = (const float*)d_in[18];
    const float* g_w2 = (const float*)d_in[19];
    const float* g_b2 = (const float*)d_in[20];
    const int* ss = (const int*)d_in[21];
    const int* rs = (const int*)d_in[22];
    const int* sa = (const int*)d_in[23];
    const int* ra = (const int*)d_in[24];
    const int* sn = (const int*)d_in[25];
    const int* rn = (const int*)d_in[26];

    short* wsb = (short*)d_ws;
    int nb = in_sizes[0] / (NE * EMB);

    prep_weights<<<407, 64, 0, stream>>>(u_w1, u_w2, w_w1, w_w2, h_w1, h_w2,
                                         u_b1, u_b2, w_b1, w_b2, h_b1, h_b2,
                                         g_w1, g_w2, wsb);
    gnn_kernel<<<nb, 256, 0, stream>>>(elec, nuc, fs, fa, fn, g_b1, g_b2,
                                       ss, rs, sa, ra, sn, rn, wsb, (float*)d_out);
}

// Round 11
// 516.879 us; speedup vs baseline: 1.0283x; 1.0283x over previous
//
#include <hip/hip_runtime.h>
#include <math.h>

#define NE 32
#define NN 8
#define EMB 256
#define TPS 32
#define E_SAME 480
#define E_ANTI 512
#define E_NE 256

// ---- ws layout (shorts) ----
#define AU1_OFF 0
#define AU2_OFF 3072
#define AW1_OFF 6144
#define AW2_OFF 9216
#define H1T_OFF 12288
#define H2T_OFF 36864
#define BIAS_OFF 39936
#define G1_OFF 40512
#define G2_OFF 130624
#define HX_OFF  196608                  // bf16 [2048][72][32]  (4,718,592 shorts)
#define ZS_OFF  4915200                 // bf16 [2048][32][96]  (6,291,456 shorts)

typedef float f32x4 __attribute__((ext_vector_type(4)));
typedef short s16x4 __attribute__((ext_vector_type(4)));
typedef short s16x8 __attribute__((ext_vector_type(8)));

__device__ __forceinline__ short f2bf(float x) {
    unsigned u = __builtin_bit_cast(unsigned, x);
    u += 0x7fffu + ((u >> 16) & 1u);
    return (short)(u >> 16);
}
__device__ __forceinline__ float bf2f(short h) {
    unsigned u = ((unsigned)(unsigned short)h) << 16;
    return __builtin_bit_cast(float, u);
}
__device__ __forceinline__ float fast_tanh(float x) {
    float e = __builtin_amdgcn_exp2f(x * 2.8853900817779268f);
    return 1.f - 2.f * __builtin_amdgcn_rcpf(e + 1.f);
}
__device__ __forceinline__ s16x8 pack8(float4 a, float4 b) {
    s16x8 r = { f2bf(a.x), f2bf(a.y), f2bf(a.z), f2bf(a.w),
                f2bf(b.x), f2bf(b.y), f2bf(b.z), f2bf(b.w) };
    return r;
}
__device__ __forceinline__ s16x8 pack8v(f32x4 a, f32x4 b) {
    s16x8 r = { f2bf(a[0]), f2bf(a[1]), f2bf(a[2]), f2bf(a[3]),
                f2bf(b[0]), f2bf(b[1]), f2bf(b[2]), f2bf(b[3]) };
    return r;
}
__device__ __forceinline__ f32x4 mfma32(s16x8 a, s16x8 b, f32x4 c) {
    return __builtin_amdgcn_mfma_f32_16x16x32_bf16(a, b, c, 0, 0, 0);
}
__device__ __forceinline__ f32x4 mfma16(s16x4 a, s16x4 b, f32x4 c) {
#if __has_builtin(__builtin_amdgcn_mfma_f32_16x16x16bf16_1k)
    return __builtin_amdgcn_mfma_f32_16x16x16bf16_1k(a, b, c, 0, 0, 0);
#else
    asm volatile("v_mfma_f32_16x16x16_bf16 %0, %1, %2, %0" : "+v"(c) : "v"(a), "v"(b));
    return c;
#endif
}

__global__ void prep_weights(const float* __restrict__ u_w1, const float* __restrict__ u_w2,
                             const float* __restrict__ w_w1, const float* __restrict__ w_w2,
                             const float* __restrict__ h_w1, const float* __restrict__ h_w2,
                             const float* __restrict__ u_b1, const float* __restrict__ u_b2,
                             const float* __restrict__ w_b1, const float* __restrict__ w_b2,
                             const float* __restrict__ h_b1, const float* __restrict__ h_b2,
                             const float* __restrict__ g_w1, const float* __restrict__ g_w2,
                             short* __restrict__ wsb)
{
    int tile = blockIdx.x, lane = threadIdx.x;
    int g = lane >> 4, q = lane & 15;
    if (tile < 6) {
        int t = tile >> 1, mt = tile & 1;
        const float* src = u_w1 + t * 1024;
        short* dst = wsb + AU1_OFF + tile * 512 + lane * 8;
        #pragma unroll
        for (int i = 0; i < 8; ++i) dst[i] = f2bf(src[(8 * g + i) * 32 + mt * 16 + q]);
    } else if (tile < 42) {
        int m = (tile - 6) / 12, idx = (tile - 6) % 12;
        int mt = (idx >> 1) & 1, ks = idx & 1, t = idx >> 2;
        const float* mp = (m == 0) ? u_w2 : (m == 1) ? w_w1 : w_w2;
        const float* src = mp + t * 1024;
        short* dst = wsb + AU2_OFF + m * 3072 + idx * 256 + lane * 4;
        #pragma unroll
        for (int i = 0; i < 4; ++i) dst[i] = f2bf(src[(ks * 16 + 4 * g + i) * 32 + mt * 16 + q]);
    } else if (tile < 90) {
        int idx = tile - 42;
        int t = idx >> 4, r = idx & 15, mt = r >> 3, ks = r & 7;
        const float* src = h_w1 + t * 8192;
        short* dst = wsb + H1T_OFF + idx * 512 + lane * 8;
        #pragma unroll
        for (int i = 0; i < 8; ++i) dst[i] = f2bf(src[(ks * 32 + 8 * g + i) * 32 + mt * 16 + q]);
    } else if (tile < 102) {
        int idx = tile - 90;
        int t = idx >> 2, mt = (idx >> 1) & 1, ks = idx & 1;
        const float* src = h_w2 + t * 1024;
        short* dst = wsb + H2T_OFF + idx * 256 + lane * 4;
        #pragma unroll
        for (int i = 0; i < 4; ++i) dst[i] = f2bf(src[(ks * 16 + 4 * g + i) * 32 + mt * 16 + q]);
    } else if (tile == 102) {
        const float* bsrc[6] = {u_b1, u_b2, w_b1, w_b2, h_b1, h_b2};
        for (int j = lane; j < 576; j += 64)
            wsb[BIAS_OFF + j] = f2bf(bsrc[j / 96][j % 96]);
    } else if (tile < 279) {
        int idx = tile - 103, nt = idx / 11, ks = idx % 11;
        short* dst = wsb + G1_OFF + idx * 512 + lane * 8;
        #pragma unroll
        for (int i = 0; i < 8; ++i)
            dst[i] = f2bf(g_w1[(size_t)(ks * 32 + 8 * g + i) * 256 + nt * 16 + q]);
    } else {
        int idx = tile - 279;
        short* dst = wsb + G2_OFF + idx * 512 + lane * 8;
        int nt = idx >> 3, ks = idx & 7;
        #pragma unroll
        for (int i = 0; i < 8; ++i)
            dst[i] = f2bf(g_w2[(size_t)(ks * 32 + 8 * g + i) * 256 + nt * 16 + q]);
    }
}

// ---------------- Kernel A: hx = h-MLP(nodes) -> ws. One wave per (b,task). ----------------
__launch_bounds__(256, 4)
__global__ void hx_kernel(const float* __restrict__ elec, const float* __restrict__ nuc,
                          const short* __restrict__ wsb, short* __restrict__ hxg)
{
    const int lane = threadIdx.x & 63, wv = threadIdx.x >> 6;
    const int g = lane >> 4, q = lane & 15;
    const int wave_gid = blockIdx.x * 4 + wv;
    const int b = wave_gid / 5, task = wave_gid % 5;

    int t, nt;
    if (task < 4) { t = task >> 1; nt = task & 1; }
    else          { t = 2; nt = 0; }
    const float* rowp = (t < 2) ? elec + ((size_t)b * NE + nt * 16 + q) * EMB
                                : nuc  + ((size_t)b * NN + (q < 8 ? q : 7)) * EMB;
    f32x4 c0 = {0.f, 0.f, 0.f, 0.f}, c1 = {0.f, 0.f, 0.f, 0.f};
    const short* wA = wsb + H1T_OFF + t * 16 * 512;
    #pragma unroll
    for (int ks = 0; ks < 8; ++ks) {
        float4 v0 = *(const float4*)(rowp + 32 * ks + 8 * g);
        float4 v1 = *(const float4*)(rowp + 32 * ks + 8 * g + 4);
        s16x8 Bf = pack8(v0, v1);
        s16x8 a0 = *(const s16x8*)(wA + ks * 512 + lane * 8);
        s16x8 a1 = *(const s16x8*)(wA + (8 + ks) * 512 + lane * 8);
        c0 = mfma32(a0, Bf, c0);
        c1 = mfma32(a1, Bf, c1);
    }
    s16x4 b1l = *(const s16x4*)(wsb + BIAS_OFF + (12 + t) * 32 + 4 * g);
    s16x4 b1h = *(const s16x4*)(wsb + BIAS_OFF + (12 + t) * 32 + 16 + 4 * g);
    s16x4 p0, p1;
    #pragma unroll
    for (int r = 0; r < 4; ++r) {
        p0[r] = f2bf(fast_tanh(c0[r] + bf2f(b1l[r])));
        p1[r] = f2bf(fast_tanh(c1[r] + bf2f(b1h[r])));
    }
    const short* wA2 = wsb + H2T_OFF + t * 4 * 256;
    f32x4 d0 = {0.f, 0.f, 0.f, 0.f}, d1 = {0.f, 0.f, 0.f, 0.f};
    d0 = mfma16(*(const s16x4*)(wA2 + 0 * 256 + lane * 4), p0, d0);
    d0 = mfma16(*(const s16x4*)(wA2 + 1 * 256 + lane * 4), p1, d0);
    d1 = mfma16(*(const s16x4*)(wA2 + 2 * 256 + lane * 4), p0, d1);
    d1 = mfma16(*(const s16x4*)(wA2 + 3 * 256 + lane * 4), p1, d1);
    if (t < 2 || q < 8) {
        s16x4 b2l = *(const s16x4*)(wsb + BIAS_OFF + (15 + t) * 32 + 4 * g);
        s16x4 b2h = *(const s16x4*)(wsb + BIAS_OFF + (15 + t) * 32 + 16 + 4 * g);
        s16x4 w0, w1;
        #pragma unroll
        for (int r = 0; r < 4; ++r) {
            w0[r] = f2bf(d0[r] + bf2f(b2l[r]));
            w1[r] = f2bf(d1[r] + bf2f(b2h[r]));
        }
        int row = t * 32 + nt * 16 + q;
        short* dst = hxg + ((size_t)b * 72 + row) * 32;
        *(s16x4*)(dst + 4 * g)      = w0;
        *(s16x4*)(dst + 16 + 4 * g) = w1;
    }
}

// ---------------- Kernel C: edge MLPs + scatter -> z' (ws). LDS = z only (12.4 KB). ----------------
__launch_bounds__(256, 4)
__global__ void edge_kernel(
    const float* __restrict__ fs,  const float* __restrict__ fa,  const float* __restrict__ fn,
    const int* __restrict__ ss, const int* __restrict__ rs,
    const int* __restrict__ sa, const int* __restrict__ ra,
    const int* __restrict__ sn, const int* __restrict__ rn,
    const short* __restrict__ wsb, const short* __restrict__ hxg,
    short* __restrict__ zsg)
{
    __shared__ __align__(16) float z_s[32 * 97];
    const int tid  = threadIdx.x;
    const int b    = blockIdx.x;
    const int lane = tid & 63, wv = tid >> 6;
    const int g    = lane >> 4, q = lane & 15;

    for (int i = tid; i < 32 * 97; i += 256) z_s[i] = 0.f;
    __syncthreads();

    #pragma unroll 1
    for (int t = 0; t < 3; ++t) {
        const float* ft; const int* snd; const int* rcv; int cnt, zc0;
        if (t == 0)      { ft = fs; snd = ss; rcv = rs; cnt = E_SAME; zc0 = 32; }
        else if (t == 1) { ft = fa; snd = sa; rcv = ra; cnt = E_ANTI; zc0 = 64; }
        else             { ft = fn; snd = sn; rcv = rn; cnt = E_NE;   zc0 = 0;  }
        s16x8 Au1_0 = *(const s16x8*)(wsb + AU1_OFF + (t * 2 + 0) * 512 + lane * 8);
        s16x8 Au1_1 = *(const s16x8*)(wsb + AU1_OFF + (t * 2 + 1) * 512 + lane * 8);
        s16x4 Au2_[4], Aw1_[4], Aw2_[4];
        #pragma unroll
        for (int i = 0; i < 4; ++i) {
            Au2_[i] = *(const s16x4*)(wsb + AU2_OFF + (t * 4 + i) * 256 + lane * 4);
            Aw1_[i] = *(const s16x4*)(wsb + AW1_OFF + (t * 4 + i) * 256 + lane * 4);
            Aw2_[i] = *(const s16x4*)(wsb + AW2_OFF + (t * 4 + i) * 256 + lane * 4);
        }
        s16x4 bb1l = *(const s16x4*)(wsb + BIAS_OFF + (0 + t) * 32 + 4 * g);
        s16x4 bb1h = *(const s16x4*)(wsb + BIAS_OFF + (0 + t) * 32 + 16 + 4 * g);
        s16x4 bb2l = *(const s16x4*)(wsb + BIAS_OFF + (3 + t) * 32 + 4 * g);
        s16x4 bb2h = *(const s16x4*)(wsb + BIAS_OFF + (3 + t) * 32 + 16 + 4 * g);
        s16x4 bb3l = *(const s16x4*)(wsb + BIAS_OFF + (6 + t) * 32 + 4 * g);
        s16x4 bb3h = *(const s16x4*)(wsb + BIAS_OFF + (6 + t) * 32 + 16 + 4 * g);
        s16x4 bb4l = *(const s16x4*)(wsb + BIAS_OFF + (9 + t) * 32 + 4 * g);
        s16x4 bb4h = *(const s16x4*)(wsb + BIAS_OFF + (9 + t) * 32 + 16 + 4 * g);
        const short* hxt = hxg + ((size_t)b * 72 + t * 32) * 32;
        int ntile = cnt >> 4;

        // prologue loads for first tile
        const float* fp = ft + ((size_t)b * cnt + wv * 16 + q) * TPS;
        float4 v0 = *(const float4*)(fp + 8 * g);
        float4 v1 = *(const float4*)(fp + 8 * g + 4);
        float4 rl = *(const float4*)(fp + 4 * g);
        float4 rh = *(const float4*)(fp + 16 + 4 * g);
        int se = snd[wv * 16 + q], re = rcv[wv * 16 + q];

        #pragma unroll 1
        for (int tt = wv; tt < ntile; tt += 4) {
            int tn = tt + 4;
            float4 n0 = {0,0,0,0}, n1 = {0,0,0,0}, nrl = {0,0,0,0}, nrh = {0,0,0,0};
            int ns = 0, nr = 0;
            if (tn < ntile) {   // prefetch next tile
                const float* np = ft + ((size_t)b * cnt + tn * 16 + q) * TPS;
                n0 = *(const float4*)(np + 8 * g);
                n1 = *(const float4*)(np + 8 * g + 4);
                nrl = *(const float4*)(np + 4 * g);
                nrh = *(const float4*)(np + 16 + 4 * g);
                ns = snd[tn * 16 + q]; nr = rcv[tn * 16 + q];
            }
            s16x8 B32 = pack8(v0, v1);
            // u layer1 (K=32)
            f32x4 c0 = {0.f,0.f,0.f,0.f}, c1 = {0.f,0.f,0.f,0.f};
            c0 = mfma32(Au1_0, B32, c0);
            c1 = mfma32(Au1_1, B32, c1);
            s16x4 p0, p1;
            #pragma unroll
            for (int r = 0; r < 4; ++r) {
                p0[r] = f2bf(fast_tanh(c0[r] + bf2f(bb1l[r])));
                p1[r] = f2bf(fast_tanh(c1[r] + bf2f(bb1h[r])));
            }
            // u layer2 (K=16 x2) + residual (f32 feats)
            f32x4 d0 = {0.f,0.f,0.f,0.f}, d1 = {0.f,0.f,0.f,0.f};
            d0 = mfma16(Au2_[0], p0, d0); d0 = mfma16(Au2_[1], p1, d0);
            d1 = mfma16(Au2_[2], p0, d1); d1 = mfma16(Au2_[3], p1, d1);
            const float* rlp = (const float*)&rl; const float* rhp = (const float*)&rh;
            #pragma unroll
            for (int r = 0; r < 4; ++r) {
                p0[r] = f2bf(rlp[r] + d0[r] + bf2f(bb2l[r]));
                p1[r] = f2bf(rhp[r] + d1[r] + bf2f(bb2h[r]));
            }
            // w layer1
            d0 = (f32x4){0.f,0.f,0.f,0.f}; d1 = (f32x4){0.f,0.f,0.f,0.f};
            d0 = mfma16(Aw1_[0], p0, d0); d0 = mfma16(Aw1_[1], p1, d0);
            d1 = mfma16(Aw1_[2], p0, d1); d1 = mfma16(Aw1_[3], p1, d1);
            #pragma unroll
            for (int r = 0; r < 4; ++r) {
                p0[r] = f2bf(fast_tanh(d0[r] + bf2f(bb3l[r])));
                p1[r] = f2bf(fast_tanh(d1[r] + bf2f(bb3h[r])));
            }
            // w layer2 -> we
            d0 = (f32x4){0.f,0.f,0.f,0.f}; d1 = (f32x4){0.f,0.f,0.f,0.f};
            d0 = mfma16(Aw2_[0], p0, d0); d0 = mfma16(Aw2_[1], p1, d0);
            d1 = mfma16(Aw2_[2], p0, d1); d1 = mfma16(Aw2_[3], p1, d1);
            // msg = we * hx[sender] ; scatter into z[receiver]
            s16x4 hlo = *(const s16x4*)(hxt + se * 32 + 4 * g);
            s16x4 hhi = *(const s16x4*)(hxt + se * 32 + 16 + 4 * g);
            float* zr = z_s + re * 97 + zc0 + 4 * g;
            #pragma unroll
            for (int r = 0; r < 4; ++r) {
                atomicAdd(zr + r,      (d0[r] + bf2f(bb4l[r])) * bf2f(hlo[r]));
                atomicAdd(zr + 16 + r, (d1[r] + bf2f(bb4h[r])) * bf2f(hhi[r]));
            }
            v0 = n0; v1 = n1; rl = nrl; rh = nrh; se = ns; re = nr;
        }
    }
    __syncthreads();

    // z' = z * scale -> ws (bf16 [32][96])
    for (int u = tid; u < 384; u += 256) {
        int r = u / 12, c8 = u - r * 12;
        float sc = (c8 < 4) ? 0.125f : ((c8 < 8) ? (1.f / 15.f) : (1.f / 16.f));
        const float* zp = z_s + r * 97 + c8 * 8;
        s16x8 v;
        #pragma unroll
        for (int j = 0; j < 8; ++j) v[j] = f2bf(zp[j] * sc);
        *(s16x8*)(zsg + (size_t)b * 3072 + r * 96 + c8 * 8) = v;
    }
}

// ---------------- Kernel E: out = elec + g-MLP([elec | z']) ----------------
__launch_bounds__(256, 4)
__global__ void upd_kernel(const float* __restrict__ elec,
                           const float* __restrict__ g_b1, const float* __restrict__ g_b2,
                           const short* __restrict__ wsb, const short* __restrict__ zsg,
                           float* __restrict__ out)
{
    __shared__ __align__(16) char smem[39424];
    short* f_s = (short*)smem;                   // [32][356]
    short* H_s = (short*)(smem + 22784);         // [32][260]

    const int tid  = threadIdx.x;
    const int b    = blockIdx.x;
    const int lane = tid & 63, wv = tid >> 6;
    const int g    = lane >> 4, q = lane & 15;

    // stage f = [elec bf16 | z']
    {
        int row = tid >> 3, ch = tid & 7;        // 32 rows x 8 chunks of 32 cols
        const float* src = elec + ((size_t)b * NE + row) * EMB + ch * 32;
        short* dst = f_s + row * 356 + ch * 32;
        #pragma unroll
        for (int i = 0; i < 4; ++i) {
            float4 v0 = *(const float4*)(src + 8 * i);
            float4 v1 = *(const float4*)(src + 8 * i + 4);
            *(s16x8*)(dst + 8 * i) = pack8(v0, v1);
        }
    }
    for (int u = tid; u < 384; u += 256) {
        int r = u / 12, c8 = u - r * 12;
        *(s16x8*)(f_s + r * 356 + 256 + c8 * 8) =
            *(const s16x8*)(zsg + (size_t)b * 3072 + r * 96 + c8 * 8);
    }
    __syncthreads();

    // E layer1: H = tanh(f @ g_w1 + g_b1)
    #pragma unroll 1
    for (int task = wv; task < 32; task += 4) {
        int mt = task >> 4, nt = task & 15;
        f32x4 acc = {0.f, 0.f, 0.f, 0.f};
        const short* ar = f_s + (mt * 16 + q) * 356 + 8 * g;
        const short* wp = wsb + G1_OFF + nt * 11 * 512 + lane * 8;
        #pragma unroll
        for (int ks = 0; ks < 11; ++ks) {
            s16x4 alo = *(const s16x4*)(ar + 32 * ks);
            s16x4 ahi = *(const s16x4*)(ar + 32 * ks + 4);
            s16x8 a = __builtin_shufflevector(alo, ahi, 0, 1, 2, 3, 4, 5, 6, 7);
            s16x8 bw = *(const s16x8*)(wp + ks * 512);
            acc = mfma32(a, bw, acc);
        }
        float bias = g_b1[nt * 16 + q];
        #pragma unroll
        for (int r = 0; r < 4; ++r)
            H_s[(mt * 16 + 4 * g + r) * 260 + nt * 16 + q] = f2bf(fast_tanh(acc[r] + bias));
    }
    __syncthreads();

    // E layer2: out = elec + H @ g_w2 + g_b2
    #pragma unroll 1
    for (int task = wv; task < 32; task += 4) {
        int mt = task >> 4, nt = task & 15;
        f32x4 acc = {0.f, 0.f, 0.f, 0.f};
        const short* ar = H_s + (mt * 16 + q) * 260 + 8 * g;
        const short* wp = wsb + G2_OFF + nt * 8 * 512 + lane * 8;
        #pragma unroll
        for (int ks = 0; ks < 8; ++ks) {
            s16x4 alo = *(const s16x4*)(ar + 32 * ks);
            s16x4 ahi = *(const s16x4*)(ar + 32 * ks + 4);
            s16x8 a = __builtin_shufflevector(alo, ahi, 0, 1, 2, 3, 4, 5, 6, 7);
            s16x8 bw = *(const s16x8*)(wp + ks * 512);
            acc = mfma32(a, bw, acc);
        }
        float bias = g_b2[nt * 16 + q];
        #pragma unroll
        for (int r = 0; r < 4; ++r) {
            int row = mt * 16 + 4 * g + r, col = nt * 16 + q;
            size_t o = ((size_t)b * NE + row) * EMB + col;
            out[o] = bf2f(f_s[row * 356 + col]) + acc[r] + bias;
        }
    }
}

extern "C" void kernel_launch(void* const* d_in, const int* in_sizes, int n_in,
                              void* d_out, int out_size, void* d_ws, size_t ws_size,
                              hipStream_t stream) {
    const float* elec = (const float*)d_in[0];
    const float* nuc  = (const float*)d_in[1];
    const float* fs   = (const float*)d_in[2];
    const float* fa   = (const float*)d_in[3];
    const float* fn   = (const float*)d_in[4];
    const float* u_w1 = (const float*)d_in[5];
    const float* u_b1 = (const float*)d_in[6];
    const float* u_w2 = (const float*)d_in[7];
    const float* u_b2 = (const float*)d_in[8];
    const float* w_w1 = (const float*)d_in[9];
    const float* w_b1 = (const float*)d_in[10];
    const float* w_w2 = (const float*)d_in[11];
    const float* w_b2 = (const float*)d_in[12];
    const float* h_w1 = (const float*)d_in[13];
    const float* h_b1 = (const float*)d_in[14];
    const float* h_w2 = (const float*)d_in[15];
    const float* h_b2 = (const float*)d_in[16];
    const float* g_w1 = (const float*)d_in[17];
    const float* g_b1 = (const float*)d_in[18];
    const float* g_w2 = (const float*)d_in[19];
    const float* g_b2 = (const float*)d_in[20];
    const int* ss = (const int*)d_in[21];
    const int* rs = (const int*)d_in[22];
    const int* sa = (const int*)d_in[23];
    const int* ra = (const int*)d_in[24];
    const int* sn = (const int*)d_in[25];
    const int* rn = (const int*)d_in[26];

    short* wsb = (short*)d_ws;
    short* hxg = wsb + HX_OFF;
    short* zsg = wsb + ZS_OFF;
    int nb = in_sizes[0] / (NE * EMB);

    prep_weights<<<407, 64, 0, stream>>>(u_w1, u_w2, w_w1, w_w2, h_w1, h_w2,
                                         u_b1, u_b2, w_b1, w_b2, h_b1, h_b2,
                                         g_w1, g_w2, wsb);
    hx_kernel<<<(nb * 5 + 3) / 4, 256, 0, stream>>>(elec, nuc, wsb, hxg);
    edge_kernel<<<nb, 256, 0, stream>>>(fs, fa, fn, ss, rs, sa, ra, sn, rn,
                                        wsb, hxg, zsg);
    upd_kernel<<<nb, 256, 0, stream>>>(elec, g_b1, g_b2, wsb, zsg, (float*)d_out);
}